// Round 1
// baseline (68.946 us; speedup 1.0000x reference)
//
#include <hip/hip_runtime.h>
#include <hip/hip_bf16.h>
#include <stdint.h>

// CACProjector: logits = x @ W^T ; distances = sqrt(max(||logits_row||^2 - 2*ALPHA*logits + ALPHA^2, 0))
// B=16384, D=768, C=1024, ALPHA=10.
// Strategy: f32->bf16 convert (ws) -> 128x128 bf16 MFMA GEMM (m97-style, swizzled LDS,
// global_load_lds width16, 2-phase double buffer) -> fused row-norm distance epilogue.

#define M_DIM 16384
#define N_DIM 1024
#define K_DIM 768
#define BM 128
#define BN 128
#define BK 64
#define NT (K_DIM / BK) // 12
#define ALPHA_F 10.0f

typedef __bf16 bf16x8 __attribute__((ext_vector_type(8)));
typedef float f32x4 __attribute__((ext_vector_type(4)));

typedef const __attribute__((address_space(1))) void* gas_ptr;
typedef __attribute__((address_space(3))) void* las_ptr;

// ---------------- convert fp32 -> bf16 (RNE via compiler), 4-wide ----------------
__global__ __launch_bounds__(256) void cvt_bf16_kernel(const float* __restrict__ in,
                                                       unsigned short* __restrict__ out,
                                                       int n4) {
  int stride = gridDim.x * blockDim.x;
  for (int i = blockIdx.x * blockDim.x + threadIdx.x; i < n4; i += stride) {
    float4 v = reinterpret_cast<const float4*>(in)[i];
    union { __bf16 h[4]; ushort4 u; } p;
    p.h[0] = (__bf16)v.x;
    p.h[1] = (__bf16)v.y;
    p.h[2] = (__bf16)v.z;
    p.h[3] = (__bf16)v.w;
    reinterpret_cast<ushort4*>(out)[i] = p.u;
  }
}

// ---------------- bf16 MFMA GEMM: C[M,N] = A[M,K] * B[N,K]^T ----------------
// 256 threads = 4 waves (2x2), each wave 64x64 = 4x4 fragments of 16x16x32.
// LDS tiles [128][64] bf16, XOR-swizzled in 16B units: slot cs holds data col16 cs^(row&7).
// global_load_lds writes linearly (base + lane*16); we pre-swizzle the GLOBAL source
// address so the linear LDS slot receives the swizzled data (rule 21 / m173 pattern).
__global__ __launch_bounds__(256, 2) void gemm_bf16_kernel(
    const unsigned short* __restrict__ A,   // M x K bf16 bits
    const unsigned short* __restrict__ B,   // N x K bf16 bits (W)
    float* __restrict__ C) {                // M x N f32
  __shared__ __align__(16) unsigned short lds[2][2][BM * BK]; // [buf][A/B] 16KB each = 64KB

  const int t = threadIdx.x;
  const int lane = t & 63;
  const int w = t >> 6;
  const int wr = w >> 1;   // wave row (0..1)
  const int wc = w & 1;    // wave col (0..1)

  // XCD-aware swizzle: nwg=1024, 8 XCDs, 128 tiles per XCD chunk.
  int bid = blockIdx.x;
  int swz = (bid & 7) * 128 + (bid >> 3);
  int tn = swz & 7;    // N_tiles = 8
  int tm = swz >> 3;   // M_tiles = 128

  const unsigned short* Abase = A + (size_t)tm * BM * K_DIM;
  const unsigned short* Bbase = B + (size_t)tn * BN * K_DIM;

  f32x4 acc[4][4] = {};

  auto stage = [&](int buf, int kt) {
    const int k0 = kt * BK;
    const int row_lo = t >> 3;     // 0..31
    const int cs = t & 7;          // 16B slot within row
#pragma unroll
    for (int i = 0; i < 4; ++i) {
      int row = i * 32 + row_lo;
      int csrc = cs ^ (row & 7);   // inverse-swizzled global source
      __builtin_amdgcn_global_load_lds(
          (gas_ptr)(const void*)(Abase + (size_t)row * K_DIM + k0 + csrc * 8),
          (las_ptr)(void*)(&lds[buf][0][0] + row * BK + cs * 8),
          16, 0, 0);
    }
#pragma unroll
    for (int i = 0; i < 4; ++i) {
      int row = i * 32 + row_lo;
      int csrc = cs ^ (row & 7);
      __builtin_amdgcn_global_load_lds(
          (gas_ptr)(const void*)(Bbase + (size_t)row * K_DIM + k0 + csrc * 8),
          (las_ptr)(void*)(&lds[buf][1][0] + row * BK + cs * 8),
          16, 0, 0);
    }
  };

  auto compute = [&](int buf) {
    const unsigned short* La = &lds[buf][0][0];
    const unsigned short* Lb = &lds[buf][1][0];
#pragma unroll
    for (int kk = 0; kk < 2; ++kk) {          // two K=32 MFMA steps per BK=64
      bf16x8 af[4], bfr[4];
#pragma unroll
      for (int mi = 0; mi < 4; ++mi) {
        int row = wr * 64 + mi * 16 + (lane & 15);
        int c16 = kk * 4 + (lane >> 4);
        int cs = c16 ^ (row & 7);             // swizzled read
        af[mi] = *(const bf16x8*)(La + row * BK + cs * 8);
      }
#pragma unroll
      for (int ni = 0; ni < 4; ++ni) {
        int row = wc * 64 + ni * 16 + (lane & 15);
        int c16 = kk * 4 + (lane >> 4);
        int cs = c16 ^ (row & 7);
        bfr[ni] = *(const bf16x8*)(Lb + row * BK + cs * 8);
      }
#pragma unroll
      for (int mi = 0; mi < 4; ++mi)
#pragma unroll
        for (int ni = 0; ni < 4; ++ni)
          acc[mi][ni] = __builtin_amdgcn_mfma_f32_16x16x32_bf16(af[mi], bfr[ni], acc[mi][ni], 0, 0, 0);
    }
  };

  // T3-minimum 2-phase loop: prefetch next tile, compute current, barrier drains.
  stage(0, 0);
  __syncthreads();
  int cur = 0;
#pragma unroll 1
  for (int kt = 0; kt < NT; ++kt) {
    if (kt + 1 < NT) stage(cur ^ 1, kt + 1);
    compute(cur);
    __syncthreads();
    cur ^= 1;
  }

  // C write: C/D layout col=lane&15, row=(lane>>4)*4+reg (m89-verified).
  float* Cb = C + (size_t)tm * BM * N_DIM + (size_t)tn * BN;
#pragma unroll
  for (int mi = 0; mi < 4; ++mi) {
#pragma unroll
    for (int ni = 0; ni < 4; ++ni) {
      int col = wc * 64 + ni * 16 + (lane & 15);
      int row0 = wr * 64 + mi * 16 + ((lane >> 4) << 2);
      f32x4 v = acc[mi][ni];
#pragma unroll
      for (int r = 0; r < 4; ++r)
        Cb[(size_t)(row0 + r) * N_DIM + col] = v[r];
    }
  }
}

// ---------------- distance epilogue: one block per row ----------------
__global__ __launch_bounds__(256) void dist_kernel(const float* __restrict__ logits,
                                                   float* __restrict__ dist) {
  __shared__ float wsum[4];
  const int row = blockIdx.x;
  const int t = threadIdx.x;
  const float4* lr = reinterpret_cast<const float4*>(logits + (size_t)row * N_DIM);
  float4 v = lr[t];
  float ss = v.x * v.x + v.y * v.y + v.z * v.z + v.w * v.w;
#pragma unroll
  for (int m = 32; m >= 1; m >>= 1) ss += __shfl_xor(ss, m, 64);
  if ((t & 63) == 0) wsum[t >> 6] = ss;
  __syncthreads();
  float sq = wsum[0] + wsum[1] + wsum[2] + wsum[3];
  const float a2 = ALPHA_F * ALPHA_F;
  float4 d;
  d.x = sqrtf(fmaxf(sq - 2.0f * ALPHA_F * v.x + a2, 0.0f));
  d.y = sqrtf(fmaxf(sq - 2.0f * ALPHA_F * v.y + a2, 0.0f));
  d.z = sqrtf(fmaxf(sq - 2.0f * ALPHA_F * v.z + a2, 0.0f));
  d.w = sqrtf(fmaxf(sq - 2.0f * ALPHA_F * v.w + a2, 0.0f));
  reinterpret_cast<float4*>(dist + (size_t)row * N_DIM)[t] = d;
}

extern "C" void kernel_launch(void* const* d_in, const int* in_sizes, int n_in,
                              void* d_out, int out_size, void* d_ws, size_t ws_size,
                              hipStream_t stream) {
  const float* x = (const float*)d_in[0];   // 16384 x 768
  const float* W = (const float*)d_in[1];   // 1024 x 768
  float* logits = (float*)d_out;                          // 16384*1024
  float* dist = logits + (size_t)M_DIM * N_DIM;           // 16384*1024

  unsigned short* xb = (unsigned short*)d_ws;             // 24 MB
  unsigned short* Wb = xb + (size_t)M_DIM * K_DIM;        // 1.5 MB

  cvt_bf16_kernel<<<2048, 256, 0, stream>>>(x, xb, M_DIM * K_DIM / 4);
  cvt_bf16_kernel<<<768, 256, 0, stream>>>(W, Wb, N_DIM * K_DIM / 4);
  gemm_bf16_kernel<<<(M_DIM / BM) * (N_DIM / BN), 256, 0, stream>>>(xb, Wb, logits);
  dist_kernel<<<M_DIM, 256, 0, stream>>>(logits, dist);
}

// Round 4
// 68.567 us; speedup vs baseline: 1.0055x; 1.0055x over previous
//
#include <hip/hip_runtime.h>
#include <hip/hip_bf16.h>
#include <stdint.h>

// CACProjector: logits = x @ W^T ; dist = sqrt(max(||row||^2 - 2*A*logit + A^2, 0))
// B=16384, D=768, C=1024. Round 4: fix global_load_lds lane mapping — HW writes
// wave-uniform base + lane*16; staging slots must be slot0=t, slot1=t+512 (NOT 2t,2t+1).
// 256x256 8-phase counted-vmcnt MFMA GEMM (T1+T2+T3/T4+T5).

#define M_DIM 16384
#define N_DIM 1024
#define K_DIM 768
#define ALPHA_F 10.0f

typedef __bf16 bf16x8 __attribute__((ext_vector_type(8)));
typedef float f32x4 __attribute__((ext_vector_type(4)));
typedef const __attribute__((address_space(1))) void* gas_ptr;
typedef __attribute__((address_space(3))) void* las_ptr;

#define WAITV(N) asm volatile("s_waitcnt vmcnt(" #N ")" ::: "memory")

static __device__ __forceinline__ void bar() {
  asm volatile("" ::: "memory");
  __builtin_amdgcn_s_barrier();
  asm volatile("" ::: "memory");
}

// ---------------- merged fp32 -> bf16 convert (x then W) ----------------
__global__ __launch_bounds__(256) void cvt_both_kernel(const float* __restrict__ x,
                                                       const float* __restrict__ Wm,
                                                       unsigned short* __restrict__ xb,
                                                       unsigned short* __restrict__ Wb) {
  const int nx4 = M_DIM * K_DIM / 4;
  const int nw4 = N_DIM * K_DIM / 4;
  int stride = gridDim.x * blockDim.x;
  for (int i = blockIdx.x * blockDim.x + threadIdx.x; i < nx4 + nw4; i += stride) {
    const float4* src;
    ushort4* dst;
    int j;
    if (i < nx4) { src = (const float4*)x; dst = (ushort4*)xb; j = i; }
    else { src = (const float4*)Wm; dst = (ushort4*)Wb; j = i - nx4; }
    float4 v = src[j];
    union { __bf16 h[4]; ushort4 u; } p;
    p.h[0] = (__bf16)v.x; p.h[1] = (__bf16)v.y;
    p.h[2] = (__bf16)v.z; p.h[3] = (__bf16)v.w;
    dst[j] = p.u;
  }
}

// ---------------- MFMA quadrant helper ----------------
template <int MI0, int NI0>
__device__ __forceinline__ void mfma_quad(f32x4 (&acc)[8][4], bf16x8 (&af)[8][2],
                                          bf16x8 (&bq)[4][2]) {
#pragma unroll
  for (int mi = 0; mi < 4; ++mi)
#pragma unroll
    for (int ni = 0; ni < 2; ++ni)
#pragma unroll
      for (int kk = 0; kk < 2; ++kk)
        acc[MI0 + mi][NI0 + ni] = __builtin_amdgcn_mfma_f32_16x16x32_bf16(
            af[MI0 + mi][kk], bq[NI0 + ni][kk], acc[MI0 + mi][NI0 + ni], 0, 0, 0);
}

// ---------------- 256x256 8-phase bf16 GEMM: C = A[M,K] * B[N,K]^T ----------------
// 512 threads = 8 waves (2M x 4N); per-wave output 128x64 (8x4 frags of 16x16x32).
// LDS [2 dbuf][4 halves: A0,A1,B0,B1][128*64] bf16 = 128 KiB (1 block/CU).
// Staging: each global_load_lds covers a contiguous 1024B wave region, lane at
// slot=lane (HW constraint). slot0=t, slot1=t+512; 16 instrs cover a 1024-slot half.
// T2 swizzle: linear LDS slot (row, cs) holds global col16 cs^(row&7) via
// pre-swizzled source; reads use cs = c16^(row&7) (rule 21).
// vmcnt ledger (iter i, k0=2i, k1=2i+1; stage = 2 loads/wave):
//   p0:+B0(k1) p1:+B1(k1) p2:+A0(k0+2) p3:+A1(k0+2) WAITV(4) -> k1 landed
//   p4:+B0(k0+2) p5:+B1(k0+2) p6:+A0(k1+2) p7:+A1(k1+2) WAITV(4) -> k0+2 landed
__global__ __launch_bounds__(512, 2) void gemm_bf16_kernel(
    const unsigned short* __restrict__ A,
    const unsigned short* __restrict__ B,
    float* __restrict__ C) {
  __shared__ __align__(16) unsigned short lds[2][4][128 * 64];

  const int t = threadIdx.x;
  const int lane = t & 63;
  const int w = t >> 6;
  const int wr = w >> 2;  // 0..1 : M-half
  const int wc = w & 3;   // 0..3 : N quarter

  // T1: XCD-aware bijective swizzle (nwg=256, 256%8==0, 32 per chunk).
  int bid = blockIdx.x;
  int swz = (bid & 7) * 32 + (bid >> 3);
  int tn = swz & 3;   // 4 N-tiles
  int tm = swz >> 2;  // 64 M-tiles

  const unsigned short* Abase = A + (size_t)tm * 256 * K_DIM;
  const unsigned short* Bbase = B + (size_t)tn * 256 * K_DIM;

  // wave-uniform-legal staging slots: byte offset = slot*16 = wave_base + lane*16
  const int s0 = t;        // slots 0..511
  const int s1 = t + 512;  // slots 512..1023
  const int r0 = s0 >> 3, c0 = s0 & 7;
  const int r1 = s1 >> 3, c1 = s1 & 7;

  auto stage = [&](int buf, int hf, int kt) {
    const unsigned short* gb =
        (hf < 2 ? Abase : Bbase) + (size_t)((hf & 1) * 128) * K_DIM + kt * 64;
    unsigned short* lb = &lds[buf][hf][0];
    {
      int cs = c0 ^ (r0 & 7);
      __builtin_amdgcn_global_load_lds((gas_ptr)(gb + (size_t)r0 * K_DIM + cs * 8),
                                       (las_ptr)(lb + s0 * 8), 16, 0, 0);
    }
    {
      int cs = c1 ^ (r1 & 7);
      __builtin_amdgcn_global_load_lds((gas_ptr)(gb + (size_t)r1 * K_DIM + cs * 8),
                                       (las_ptr)(lb + s1 * 8), 16, 0, 0);
    }
  };

  f32x4 acc[8][4] = {};
  bf16x8 af[8][2];
  bf16x8 bq[4][2];

  auto ld_a = [&](int buf, int mi, int kk) -> bf16x8 {
    int row = mi * 16 + (lane & 15);
    int cs = (kk * 4 + (lane >> 4)) ^ (row & 7);
    return *(const bf16x8*)(&lds[buf][wr][0] + row * 64 + cs * 8);
  };
  auto ld_b = [&](int buf, int ni, int kk) -> bf16x8 {
    int row = (wc & 1) * 64 + ni * 16 + (lane & 15);
    int cs = (kk * 4 + (lane >> 4)) ^ (row & 7);
    return *(const bf16x8*)(&lds[buf][2 + (wc >> 1)][0] + row * 64 + cs * 8);
  };

  auto loadA = [&](int buf, int m0) {
#pragma unroll
    for (int mi = 0; mi < 4; ++mi) {
      af[m0 + mi][0] = ld_a(buf, m0 + mi, 0);
      af[m0 + mi][1] = ld_a(buf, m0 + mi, 1);
    }
  };
  auto loadB = [&](int buf, int n0) {
#pragma unroll
    for (int ni = 0; ni < 2; ++ni) {
      bq[n0 + ni][0] = ld_b(buf, n0 + ni, 0);
      bq[n0 + ni][1] = ld_b(buf, n0 + ni, 1);
    }
  };

  // Prologue: all 4 halves of kt0, A-halves of kt1; land kt0; 4 loads in flight.
  stage(0, 0, 0); stage(0, 1, 0); stage(0, 2, 0); stage(0, 3, 0);
  stage(1, 0, 1); stage(1, 1, 1);
  WAITV(4);
  bar();

#pragma unroll 1
  for (int i = 0; i < 5; ++i) {
    const int kt0 = 2 * i, kt1 = 2 * i + 1;
    // ---------- K-tile kt0 (buf 0) ----------
    loadA(0, 0); loadB(0, 0);
    stage(1, 2, kt1);
    bar();
    __builtin_amdgcn_s_setprio(1); mfma_quad<0, 0>(acc, af, bq); __builtin_amdgcn_s_setprio(0);
    bar();
    loadA(0, 4);
    stage(1, 3, kt1);
    bar();
    __builtin_amdgcn_s_setprio(1); mfma_quad<4, 0>(acc, af, bq); __builtin_amdgcn_s_setprio(0);
    bar();
    loadB(0, 2);
    stage(0, 0, kt0 + 2);
    bar();
    __builtin_amdgcn_s_setprio(1); mfma_quad<0, 2>(acc, af, bq); __builtin_amdgcn_s_setprio(0);
    bar();
    stage(0, 1, kt0 + 2);
    bar();
    __builtin_amdgcn_s_setprio(1); mfma_quad<4, 2>(acc, af, bq); __builtin_amdgcn_s_setprio(0);
    WAITV(4);
    bar();
    // ---------- K-tile kt1 (buf 1) ----------
    loadA(1, 0); loadB(1, 0);
    stage(0, 2, kt0 + 2);
    bar();
    __builtin_amdgcn_s_setprio(1); mfma_quad<0, 0>(acc, af, bq); __builtin_amdgcn_s_setprio(0);
    bar();
    loadA(1, 4);
    stage(0, 3, kt0 + 2);
    bar();
    __builtin_amdgcn_s_setprio(1); mfma_quad<4, 0>(acc, af, bq); __builtin_amdgcn_s_setprio(0);
    bar();
    loadB(1, 2);
    stage(1, 0, kt1 + 2);
    bar();
    __builtin_amdgcn_s_setprio(1); mfma_quad<0, 2>(acc, af, bq); __builtin_amdgcn_s_setprio(0);
    bar();
    stage(1, 1, kt1 + 2);
    bar();
    __builtin_amdgcn_s_setprio(1); mfma_quad<4, 2>(acc, af, bq); __builtin_amdgcn_s_setprio(0);
    WAITV(4);
    bar();
  }

  // ---------- Epilogue kt=10 (buf 0): stage kt11's B halves ----------
  loadA(0, 0); loadB(0, 0);
  stage(1, 2, 11);
  bar();
  __builtin_amdgcn_s_setprio(1); mfma_quad<0, 0>(acc, af, bq); __builtin_amdgcn_s_setprio(0);
  bar();
  loadA(0, 4);
  stage(1, 3, 11);
  bar();
  __builtin_amdgcn_s_setprio(1); mfma_quad<4, 0>(acc, af, bq); __builtin_amdgcn_s_setprio(0);
  bar();
  loadB(0, 2);
  bar();
  __builtin_amdgcn_s_setprio(1); mfma_quad<0, 2>(acc, af, bq); __builtin_amdgcn_s_setprio(0);
  bar();
  __builtin_amdgcn_s_setprio(1); mfma_quad<4, 2>(acc, af, bq); __builtin_amdgcn_s_setprio(0);
  WAITV(0);
  bar();
  // ---------- kt=11 (buf 1): fully landed, no further LDS writes ----------
  loadA(1, 0); loadB(1, 0);
  loadA(1, 4); loadB(1, 2);
  __builtin_amdgcn_s_setprio(1);
  mfma_quad<0, 0>(acc, af, bq);
  mfma_quad<4, 0>(acc, af, bq);
  mfma_quad<0, 2>(acc, af, bq);
  mfma_quad<4, 2>(acc, af, bq);
  __builtin_amdgcn_s_setprio(0);

  // C write: col = lane&15 within ni frag; rows = (lane>>4)*4 + r within mi frag.
  float* Cb = C + ((size_t)tm * 256 + wr * 128) * N_DIM + tn * 256 + wc * 64;
#pragma unroll
  for (int mi = 0; mi < 8; ++mi)
#pragma unroll
    for (int ni = 0; ni < 4; ++ni) {
      int col = ni * 16 + (lane & 15);
      int row0 = mi * 16 + ((lane >> 4) << 2);
      f32x4 v = acc[mi][ni];
#pragma unroll
      for (int r = 0; r < 4; ++r)
        Cb[(size_t)(row0 + r) * N_DIM + col] = v[r];
    }
}

// ---------------- distance epilogue: one block per row ----------------
__global__ __launch_bounds__(256) void dist_kernel(const float* __restrict__ logits,
                                                   float* __restrict__ dist) {
  __shared__ float wsum[4];
  const int row = blockIdx.x;
  const int t = threadIdx.x;
  const float4* lr = reinterpret_cast<const float4*>(logits + (size_t)row * N_DIM);
  float4 v = lr[t];
  float ss = v.x * v.x + v.y * v.y + v.z * v.z + v.w * v.w;
#pragma unroll
  for (int m = 32; m >= 1; m >>= 1) ss += __shfl_xor(ss, m, 64);
  if ((t & 63) == 0) wsum[t >> 6] = ss;
  __syncthreads();
  float sq = wsum[0] + wsum[1] + wsum[2] + wsum[3];
  const float a2 = ALPHA_F * ALPHA_F;
  float4 d;
  d.x = sqrtf(fmaxf(sq - 2.0f * ALPHA_F * v.x + a2, 0.0f));
  d.y = sqrtf(fmaxf(sq - 2.0f * ALPHA_F * v.y + a2, 0.0f));
  d.z = sqrtf(fmaxf(sq - 2.0f * ALPHA_F * v.z + a2, 0.0f));
  d.w = sqrtf(fmaxf(sq - 2.0f * ALPHA_F * v.w + a2, 0.0f));
  reinterpret_cast<float4*>(dist + (size_t)row * N_DIM)[t] = d;
}

extern "C" void kernel_launch(void* const* d_in, const int* in_sizes, int n_in,
                              void* d_out, int out_size, void* d_ws, size_t ws_size,
                              hipStream_t stream) {
  const float* x = (const float*)d_in[0];  // 16384 x 768
  const float* W = (const float*)d_in[1];  // 1024 x 768
  float* logits = (float*)d_out;
  float* dist = logits + (size_t)M_DIM * N_DIM;

  unsigned short* xb = (unsigned short*)d_ws;
  unsigned short* Wb = xb + (size_t)M_DIM * K_DIM;

  cvt_both_kernel<<<2048, 256, 0, stream>>>(x, W, xb, Wb);
  gemm_bf16_kernel<<<(M_DIM / 256) * (N_DIM / 256), 512, 0, stream>>>(xb, Wb, logits);
  dist_kernel<<<M_DIM, 256, 0, stream>>>(logits, dist);
}